// Round 1
// baseline (118.639 us; speedup 1.0000x reference)
//
#include <hip/hip_runtime.h>
#include <math.h>

#define NK 32           // knots
#define NP 36           // NK + 4 (system size)
#define NA 37           // augmented columns

// ---------------------------------------------------------------------------
// Stage 1: build and solve the (36x36) bordered TPS system per (batch,channel)
// in fp64 via Gaussian elimination with partial pivoting. One 64-thread block
// per system; 24 blocks total. Writes W as [B][36][4] floats (float4-padded).
// ---------------------------------------------------------------------------
__global__ __launch_bounds__(64) void tps_solve(const float* __restrict__ params,
                                                float* __restrict__ Wout) {
    int b  = blockIdx.x / 3;
    int ch = blockIdx.x % 3;
    const float* pp = params + (size_t)b * (6 * NK + 3);

    __shared__ double A[NP * NA];
    __shared__ double xsol[NP];
    __shared__ int piv;
    int tid = threadIdx.x;

    double lam = (double)pp[6 * NK + ch];

    // Build augmented matrix [K | v]
    for (int idx = tid; idx < NP * NA; idx += 64) {
        int r = idx / NA, c = idx % NA;
        double v;
        if (r < NK) {
            if (c < NK) {
                if (r == c) {
                    v = lam;                       // dd diag = 0, + lambda*I
                } else {
                    double dx = (double)pp[r*3+0] - (double)pp[c*3+0];
                    double dy = (double)pp[r*3+1] - (double)pp[c*3+1];
                    double dz = (double)pp[r*3+2] - (double)pp[c*3+2];
                    v = sqrt(dx*dx + dy*dy + dz*dz);
                }
            } else if (c == NK) {
                v = 1.0;                           // ones column
            } else if (c < NP) {
                v = (double)pp[r*3 + (c - 33)];    // xs columns
            } else {
                v = (double)pp[3*NK + r*3 + ch];   // rhs: ys[:, r, ch]
            }
        } else {
            if (c < NK) {
                v = (r == NK) ? 1.0 : (double)pp[c*3 + (r - 33)];  // [1; xs^T]
            } else {
                v = 0.0;                           // zero 4x4 block + zero rhs
            }
        }
        A[idx] = v;
    }
    __syncthreads();

    // Forward elimination with partial pivoting
    for (int k = 0; k < NP; ++k) {
        // pivot search: lane r holds |A[r][k]|, butterfly max across the wave
        double val = -1.0; int row = k;
        if (tid >= k && tid < NP) { val = fabs(A[tid*NA + k]); row = tid; }
        for (int off = 32; off > 0; off >>= 1) {
            double ov  = __shfl_xor(val, off);
            int    orw = __shfl_xor(row, off);
            if (ov > val) { val = ov; row = orw; }
        }
        if (tid == 0) piv = row;
        __syncthreads();
        int pr = piv;
        if (pr != k) {
            for (int c = tid; c < NA; c += 64) {
                double t = A[k*NA + c]; A[k*NA + c] = A[pr*NA + c]; A[pr*NA + c] = t;
            }
        }
        __syncthreads();
        double invp = 1.0 / A[k*NA + k];
        if (tid > k && tid < NP) {
            double f = A[tid*NA + k] * invp;
            for (int c = k; c < NA; ++c)
                A[tid*NA + c] -= f * A[k*NA + c];
        }
        __syncthreads();
    }

    // Back substitution (serial, tiny)
    if (tid == 0) {
        for (int r = NP - 1; r >= 0; --r) {
            double s = A[r*NA + NA - 1];
            for (int c = r + 1; c < NP; ++c) s -= A[r*NA + c] * xsol[c];
            xsol[r] = s / A[r*NA + r];
        }
    }
    __syncthreads();

    if (tid < NP) {
        Wout[(size_t)b * NP * 4 + tid * 4 + ch] = (float)xsol[tid];
        if (ch == 0) Wout[(size_t)b * NP * 4 + tid * 4 + 3] = 0.0f;  // pad
    }
}

// ---------------------------------------------------------------------------
// Stage 2: per-pixel spline evaluation.
// fimg = raw.reshape(B, HW, 3) is a linear reinterpretation: pixel p = 3
// consecutive floats at p*3; output reshape is identity on flat layout.
// Each thread handles 4 pixels = 12 consecutive floats = 3 aligned float4.
// Knots (32) and weights (36) staged in LDS as float4.
// ---------------------------------------------------------------------------
__global__ __launch_bounds__(256) void spline_apply(const float* __restrict__ raw,
                                                    const float* __restrict__ params,
                                                    const float4* __restrict__ Wk,
                                                    float* __restrict__ out,
                                                    int HW, int bpb) {
    __shared__ float4 sX[NK];
    __shared__ float4 sW[NP];

    int b   = blockIdx.x / bpb;
    int blk = blockIdx.x % bpb;
    int tid = threadIdx.x;

    const float* pp = params + (size_t)b * (6 * NK + 3);
    if (tid < NK) sX[tid] = make_float4(pp[tid*3], pp[tid*3+1], pp[tid*3+2], 0.f);
    if (tid < NP) sW[tid] = Wk[(size_t)b * NP + tid];
    __syncthreads();

    int p4 = blk * 256 + tid;             // 4-pixel group index within batch
    if (p4 * 4 >= HW) return;

    size_t off = (size_t)b * HW * 3 + (size_t)p4 * 12;
    const float4* src = (const float4*)(raw + off);
    float4 v0 = src[0], v1 = src[1], v2 = src[2];
    float f[12] = {v0.x, v0.y, v0.z, v0.w,
                   v1.x, v1.y, v1.z, v1.w,
                   v2.x, v2.y, v2.z, v2.w};

    float4 wb  = sW[NK];                   // bias row (ones column)
    float4 w33 = sW[NK+1], w34 = sW[NK+2], w35 = sW[NK+3];  // linear rows
    float acc[12];
    #pragma unroll
    for (int p = 0; p < 4; ++p) {
        float c0 = f[p*3+0], c1 = f[p*3+1], c2 = f[p*3+2];
        acc[p*3+0] = wb.x + c0*w33.x + c1*w34.x + c2*w35.x;
        acc[p*3+1] = wb.y + c0*w33.y + c1*w34.y + c2*w35.y;
        acc[p*3+2] = wb.z + c0*w33.z + c1*w34.z + c2*w35.z;
    }

    #pragma unroll 4
    for (int k = 0; k < NK; ++k) {
        float4 x = sX[k];
        float4 w = sW[k];
        #pragma unroll
        for (int p = 0; p < 4; ++p) {
            float dx = f[p*3+0] - x.x;
            float dy = f[p*3+1] - x.y;
            float dz = f[p*3+2] - x.z;
            float d  = sqrtf(dx*dx + dy*dy + dz*dz);
            acc[p*3+0] += d * w.x;
            acc[p*3+1] += d * w.y;
            acc[p*3+2] += d * w.z;
        }
    }

    float4* dst = (float4*)(out + off);
    dst[0] = make_float4(acc[0], acc[1], acc[2],  acc[3]);
    dst[1] = make_float4(acc[4], acc[5], acc[6],  acc[7]);
    dst[2] = make_float4(acc[8], acc[9], acc[10], acc[11]);
}

extern "C" void kernel_launch(void* const* d_in, const int* in_sizes, int n_in,
                              void* d_out, int out_size, void* d_ws, size_t ws_size,
                              hipStream_t stream) {
    const float* raw    = (const float*)d_in[0];
    const float* params = (const float*)d_in[1];
    float* out = (float*)d_out;
    float* Wk  = (float*)d_ws;                 // [B][36][4] floats = 4.6 KB

    int B  = in_sizes[1] / (6 * NK + 3);
    int HW = in_sizes[0] / (B * 3);

    tps_solve<<<dim3(B * 3), dim3(64), 0, stream>>>(params, Wk);

    int groups = HW / 4;                       // HW = 200704, divisible by 4
    int bpb = (groups + 255) / 256;
    spline_apply<<<dim3(B * bpb), dim3(256), 0, stream>>>(
        raw, params, (const float4*)Wk, out, HW, bpb);
}

// Round 3
// 70.658 us; speedup vs baseline: 1.6791x; 1.6791x over previous
//
#include <hip/hip_runtime.h>
#include <math.h>

#define NK 32           // knots
#define NP 36           // NK + 4 (system size)
#define NA 37           // augmented columns (incl. rhs)
#define PX 8            // pixels per thread in apply

// hardware v_sqrt_f32 (~1 ulp) — __sqrtf collides with glibc math.h macros
__device__ __forceinline__ float hw_sqrtf(float x) {
    return __builtin_amdgcn_sqrtf(x);
}

// broadcast a double from lane `sl` (wave-uniform SGPR lane id) to all lanes
__device__ __forceinline__ double bcast_lane(double v, int sl) {
    union { double d; int i[2]; } u, r;
    u.d = v;
    r.i[0] = __builtin_amdgcn_readlane(u.i[0], sl);
    r.i[1] = __builtin_amdgcn_readlane(u.i[1], sl);
    return r.d;
}

// ---------------------------------------------------------------------------
// Stage 1: one wave per (batch,channel) system. Lane r owns row r of the
// 36x37 augmented matrix in registers (fp64). Gauss-Jordan with partial
// pivoting: pivot row broadcast via v_readlane (no LDS round-trips, no
// barriers). The lane chosen at step k ends with x[k] in row[36].
// ---------------------------------------------------------------------------
__global__ __launch_bounds__(64) void tps_solve(const float* __restrict__ params,
                                                float* __restrict__ Wout) {
    int sys = blockIdx.x;
    int b   = sys / 3;
    int ch  = sys % 3;
    const float* pp = params + (size_t)b * (6 * NK + 3);

    __shared__ float sxs[NK][3];
    int tid = threadIdx.x;
    for (int i = tid; i < NK * 3; i += 64) sxs[i / 3][i % 3] = pp[i];
    __syncthreads();

    float lam = pp[6 * NK + ch];

    // Build row `tid` in registers. Distances in fp32 (matches reference).
    double row[NA];
    #pragma unroll
    for (int c = 0; c < NA; ++c) row[c] = 0.0;

    if (tid < NK) {
        float x0 = sxs[tid][0], x1 = sxs[tid][1], x2 = sxs[tid][2];
        #pragma unroll
        for (int c = 0; c < NK; ++c) {
            if (c == tid) continue;  // diagonal set below
            float dx = x0 - sxs[c][0];
            float dy = x1 - sxs[c][1];
            float dz = x2 - sxs[c][2];
            row[c] = (double)hw_sqrtf(dx*dx + dy*dy + dz*dz);
        }
        row[tid] = (double)lam;          // dd diag = 0, + lambda
        row[32]  = 1.0;
        row[33]  = (double)x0;
        row[34]  = (double)x1;
        row[35]  = (double)x2;
        row[36]  = (double)pp[3*NK + tid*3 + ch];   // rhs = ys[tid][ch]
    } else if (tid < NP) {
        // bottom rows: [1...1; xs^T] in cols 0..31, zeros elsewhere
        #pragma unroll
        for (int c = 0; c < NK; ++c)
            row[c] = (tid == 32) ? 1.0 : (double)sxs[c][tid - 33];
    }

    bool used = (tid >= NP);
    int  kown = -1;

    #pragma unroll
    for (int k = 0; k < NP; ++k) {
        // --- pivot selection: max |row[k]| over unused lanes, butterfly ---
        float mag = used ? -1.0f : (float)fabs(row[k]);
        int   rid = tid;
        #pragma unroll
        for (int off = 32; off > 0; off >>= 1) {
            float om   = __shfl_xor(mag, off);
            int   orid = __shfl_xor(rid, off);
            if (om > mag || (om == mag && orid < rid)) { mag = om; rid = orid; }
        }
        int prid = __builtin_amdgcn_readfirstlane(rid);

        double pk  = bcast_lane(row[k], prid);
        double inv = 1.0 / pk;
        double f   = row[k];
        bool   isp = (tid == prid);
        if (isp) { used = true; kown = k; }

        // --- eliminate column k from every other row (Gauss-Jordan) ---
        // columns < k hold eliminated residuals (~0): skip them.
        #pragma unroll
        for (int c = 0; c < NA; ++c) {
            if (c < k) continue;
            double pc = bcast_lane(row[c], prid) * inv;  // normalized pivot row
            if (isp) row[c] = pc;
            else     row[c] -= f * pc;
        }
    }

    // lane chosen at step k holds x[k] = row[36]
    if (kown >= 0)
        Wout[((size_t)b * NP + kown) * 4 + ch] = (float)row[36];
}

// ---------------------------------------------------------------------------
// Stage 2: per-pixel spline evaluation, PX=8 pixels (24 floats = 6 float4)
// per thread. fimg = raw.reshape(B,HW,3) is a linear reinterpretation, and
// the output reshape is the identity on flat layout.
// ---------------------------------------------------------------------------
__global__ __launch_bounds__(256) void spline_apply(const float* __restrict__ raw,
                                                    const float* __restrict__ params,
                                                    const float4* __restrict__ Wk,
                                                    float* __restrict__ out,
                                                    int HW) {
    __shared__ float4 sX[NK];
    __shared__ float4 sW[NP];

    int b   = blockIdx.y;
    int tid = threadIdx.x;

    const float* pp = params + (size_t)b * (6 * NK + 3);
    if (tid < NK) sX[tid] = make_float4(pp[tid*3], pp[tid*3+1], pp[tid*3+2], 0.f);
    if (tid < NP) sW[tid] = Wk[(size_t)b * NP + tid];
    __syncthreads();

    int p8 = blockIdx.x * 256 + tid;          // 8-pixel group within batch
    if (p8 * PX >= HW) return;

    size_t off = (size_t)b * HW * 3 + (size_t)p8 * (PX * 3);
    const float4* src = (const float4*)(raw + off);
    float f[PX * 3];
    #pragma unroll
    for (int j = 0; j < PX * 3 / 4; ++j) {
        float4 v = src[j];
        f[j*4+0] = v.x; f[j*4+1] = v.y; f[j*4+2] = v.z; f[j*4+3] = v.w;
    }

    float4 wb  = sW[NK];                                    // bias row
    float4 w33 = sW[NK+1], w34 = sW[NK+2], w35 = sW[NK+3];  // linear rows
    float acc[PX * 3];
    #pragma unroll
    for (int p = 0; p < PX; ++p) {
        float c0 = f[p*3+0], c1 = f[p*3+1], c2 = f[p*3+2];
        acc[p*3+0] = wb.x + c0*w33.x + c1*w34.x + c2*w35.x;
        acc[p*3+1] = wb.y + c0*w33.y + c1*w34.y + c2*w35.y;
        acc[p*3+2] = wb.z + c0*w33.z + c1*w34.z + c2*w35.z;
    }

    #pragma unroll 4
    for (int k = 0; k < NK; ++k) {
        float4 x = sX[k];
        float4 w = sW[k];
        #pragma unroll
        for (int p = 0; p < PX; ++p) {
            float dx = f[p*3+0] - x.x;
            float dy = f[p*3+1] - x.y;
            float dz = f[p*3+2] - x.z;
            float d  = hw_sqrtf(dx*dx + dy*dy + dz*dz);
            acc[p*3+0] += d * w.x;
            acc[p*3+1] += d * w.y;
            acc[p*3+2] += d * w.z;
        }
    }

    float4* dst = (float4*)(out + off);
    #pragma unroll
    for (int j = 0; j < PX * 3 / 4; ++j)
        dst[j] = make_float4(acc[j*4+0], acc[j*4+1], acc[j*4+2], acc[j*4+3]);
}

extern "C" void kernel_launch(void* const* d_in, const int* in_sizes, int n_in,
                              void* d_out, int out_size, void* d_ws, size_t ws_size,
                              hipStream_t stream) {
    const float* raw    = (const float*)d_in[0];
    const float* params = (const float*)d_in[1];
    float* out = (float*)d_out;
    float* Wk  = (float*)d_ws;                 // [B][36][4] floats

    int B  = in_sizes[1] / (6 * NK + 3);
    int HW = in_sizes[0] / (B * 3);

    tps_solve<<<dim3(B * 3), dim3(64), 0, stream>>>(params, Wk);

    int groups = HW / PX;                      // HW = 200704, divisible by 8
    int bpb = (groups + 255) / 256;
    spline_apply<<<dim3(bpb, B), dim3(256), 0, stream>>>(
        raw, params, (const float4*)Wk, out, HW);
}

// Round 4
// 51.673 us; speedup vs baseline: 2.2959x; 1.3674x over previous
//
#include <hip/hip_runtime.h>
#include <math.h>

#define NK 32           // knots
#define NP 36           // NK + 4 (system size)
#define NA 37           // augmented columns (incl. rhs)
#define PX 8            // pixels per thread in apply

// hardware v_sqrt_f32 (~1 ulp) — __sqrtf collides with glibc math.h macros
__device__ __forceinline__ float hw_sqrtf(float x) {
    return __builtin_amdgcn_sqrtf(x);
}

// broadcast a double from lane `sl` (wave-uniform SGPR lane id) to all lanes
__device__ __forceinline__ double bcast_lane(double v, int sl) {
    union { double d; int i[2]; } u, r;
    u.d = v;
    r.i[0] = __builtin_amdgcn_readlane(u.i[0], sl);
    r.i[1] = __builtin_amdgcn_readlane(u.i[1], sl);
    return r.d;
}

// ---------------------------------------------------------------------------
// One Gauss-Jordan step with compile-time K: template instantiation guarantees
// every row[] index is a constant -> array stays in VGPRs (no scratch).
// ---------------------------------------------------------------------------
template<int K>
__device__ __forceinline__ void gj_step(double (&row)[NA], bool& used,
                                        int& kown, int tid) {
    // --- pivot select: argmax |row[K]| over unused lanes, packed u32 ---
    // |x| as IEEE bits is monotonic for x>=0; low 6 bits carry the lane id.
    float mag = (float)fabs(row[K]);
    unsigned packed = (__float_as_uint(mag) & 0xFFFFFFC0u) | (unsigned)tid;
    if (used) packed = 0u;
    #pragma unroll
    for (int off = 32; off > 0; off >>= 1) {
        unsigned o = (unsigned)__shfl_xor((int)packed, off);
        packed = packed > o ? packed : o;
    }
    int prid = __builtin_amdgcn_readfirstlane((int)(packed & 63u));

    double pk  = bcast_lane(row[K], prid);
    double inv = 1.0 / pk;
    double f   = row[K];
    bool   isp = (tid == prid);
    if (isp) { used = true; kown = K; }

    // --- eliminate column K from every row (Gauss-Jordan). Skip c<=K:
    // those columns hold eliminated residuals that are never read again.
    #pragma unroll
    for (int c = K + 1; c < NA; ++c) {
        double pc = bcast_lane(row[c], prid) * inv;   // normalized pivot row
        row[c] = isp ? pc : row[c] - f * pc;
    }
}

template<int K>
__device__ __forceinline__ void gj_all(double (&row)[NA], bool& used,
                                       int& kown, int tid) {
    if constexpr (K < NP) {
        gj_step<K>(row, used, kown, tid);
        gj_all<K + 1>(row, used, kown, tid);
    }
}

// ---------------------------------------------------------------------------
// Stage 1: one wave per (batch,channel) system. Lane r owns row r of the
// 36x37 augmented matrix in fp64 VGPRs. Gauss-Jordan with partial pivoting;
// pivot row broadcast via v_readlane (no LDS round-trips, no barriers).
// The lane chosen at step k ends with x[k] in row[36].
// ---------------------------------------------------------------------------
__global__ __launch_bounds__(64, 1) void tps_solve(const float* __restrict__ params,
                                                   float* __restrict__ Wout) {
    int sys = blockIdx.x;
    int b   = sys / 3;
    int ch  = sys % 3;
    const float* pp = params + (size_t)b * (6 * NK + 3);

    __shared__ float sxs[NK][3];
    int tid = threadIdx.x;
    for (int i = tid; i < NK * 3; i += 64) sxs[i / 3][i % 3] = pp[i];
    __syncthreads();

    float lam = pp[6 * NK + ch];

    // Build row `tid` in registers. Distances in fp32 (matches reference).
    double row[NA];
    #pragma unroll
    for (int c = 0; c < NA; ++c) row[c] = 0.0;

    if (tid < NK) {
        float x0 = sxs[tid][0], x1 = sxs[tid][1], x2 = sxs[tid][2];
        #pragma unroll
        for (int c = 0; c < NK; ++c) {
            if (c == tid) continue;  // diagonal set below
            float dx = x0 - sxs[c][0];
            float dy = x1 - sxs[c][1];
            float dz = x2 - sxs[c][2];
            row[c] = (double)hw_sqrtf(dx*dx + dy*dy + dz*dz);
        }
        row[tid] = (double)lam;          // dd diag = 0, + lambda
        row[32]  = 1.0;
        row[33]  = (double)x0;
        row[34]  = (double)x1;
        row[35]  = (double)x2;
        row[36]  = (double)pp[3*NK + tid*3 + ch];   // rhs = ys[tid][ch]
    } else if (tid < NP) {
        // bottom rows: [1...1; xs^T] in cols 0..31, zeros elsewhere
        #pragma unroll
        for (int c = 0; c < NK; ++c)
            row[c] = (tid == 32) ? 1.0 : (double)sxs[c][tid - 33];
    }

    bool used = (tid >= NP);   // lanes 36..63 never pivot
    int  kown = -1;

    gj_all<0>(row, used, kown, tid);

    // lane chosen at step k holds x[k] = row[36]
    if (kown >= 0)
        Wout[((size_t)b * NP + kown) * 4 + ch] = (float)row[36];
}

// ---------------------------------------------------------------------------
// Stage 2: per-pixel spline evaluation, PX=8 pixels (24 floats = 6 float4)
// per thread. fimg = raw.reshape(B,HW,3) is a linear reinterpretation, and
// the output reshape is the identity on flat layout. (unchanged this round)
// ---------------------------------------------------------------------------
__global__ __launch_bounds__(256) void spline_apply(const float* __restrict__ raw,
                                                    const float* __restrict__ params,
                                                    const float4* __restrict__ Wk,
                                                    float* __restrict__ out,
                                                    int HW) {
    __shared__ float4 sX[NK];
    __shared__ float4 sW[NP];

    int b   = blockIdx.y;
    int tid = threadIdx.x;

    const float* pp = params + (size_t)b * (6 * NK + 3);
    if (tid < NK) sX[tid] = make_float4(pp[tid*3], pp[tid*3+1], pp[tid*3+2], 0.f);
    if (tid < NP) sW[tid] = Wk[(size_t)b * NP + tid];
    __syncthreads();

    int p8 = blockIdx.x * 256 + tid;          // 8-pixel group within batch
    if (p8 * PX >= HW) return;

    size_t off = (size_t)b * HW * 3 + (size_t)p8 * (PX * 3);
    const float4* src = (const float4*)(raw + off);
    float f[PX * 3];
    #pragma unroll
    for (int j = 0; j < PX * 3 / 4; ++j) {
        float4 v = src[j];
        f[j*4+0] = v.x; f[j*4+1] = v.y; f[j*4+2] = v.z; f[j*4+3] = v.w;
    }

    float4 wb  = sW[NK];                                    // bias row
    float4 w33 = sW[NK+1], w34 = sW[NK+2], w35 = sW[NK+3];  // linear rows
    float acc[PX * 3];
    #pragma unroll
    for (int p = 0; p < PX; ++p) {
        float c0 = f[p*3+0], c1 = f[p*3+1], c2 = f[p*3+2];
        acc[p*3+0] = wb.x + c0*w33.x + c1*w34.x + c2*w35.x;
        acc[p*3+1] = wb.y + c0*w33.y + c1*w34.y + c2*w35.y;
        acc[p*3+2] = wb.z + c0*w33.z + c1*w34.z + c2*w35.z;
    }

    #pragma unroll 4
    for (int k = 0; k < NK; ++k) {
        float4 x = sX[k];
        float4 w = sW[k];
        #pragma unroll
        for (int p = 0; p < PX; ++p) {
            float dx = f[p*3+0] - x.x;
            float dy = f[p*3+1] - x.y;
            float dz = f[p*3+2] - x.z;
            float d  = hw_sqrtf(dx*dx + dy*dy + dz*dz);
            acc[p*3+0] += d * w.x;
            acc[p*3+1] += d * w.y;
            acc[p*3+2] += d * w.z;
        }
    }

    float4* dst = (float4*)(out + off);
    #pragma unroll
    for (int j = 0; j < PX * 3 / 4; ++j)
        dst[j] = make_float4(acc[j*4+0], acc[j*4+1], acc[j*4+2], acc[j*4+3]);
}

extern "C" void kernel_launch(void* const* d_in, const int* in_sizes, int n_in,
                              void* d_out, int out_size, void* d_ws, size_t ws_size,
                              hipStream_t stream) {
    const float* raw    = (const float*)d_in[0];
    const float* params = (const float*)d_in[1];
    float* out = (float*)d_out;
    float* Wk  = (float*)d_ws;                 // [B][36][4] floats

    int B  = in_sizes[1] / (6 * NK + 3);
    int HW = in_sizes[0] / (B * 3);

    tps_solve<<<dim3(B * 3), dim3(64), 0, stream>>>(params, Wk);

    int groups = HW / PX;                      // HW = 200704, divisible by 8
    int bpb = (groups + 255) / 256;
    spline_apply<<<dim3(bpb, B), dim3(256), 0, stream>>>(
        raw, params, (const float4*)Wk, out, HW);
}

// Round 5
// 48.711 us; speedup vs baseline: 2.4356x; 1.0608x over previous
//
#include <hip/hip_runtime.h>
#include <math.h>

#define NK 32           // knots
#define NP 36           // NK + 4 (system size)
#define NA 37           // augmented columns (incl. rhs)
#define PX 8            // pixels per thread in apply

// hardware v_sqrt_f32 (~1 ulp) — __sqrtf collides with glibc math.h macros
__device__ __forceinline__ float hw_sqrtf(float x) {
    return __builtin_amdgcn_sqrtf(x);
}

// broadcast a double from lane `sl` (wave-uniform SGPR lane id) to all lanes
__device__ __forceinline__ double bcast_lane(double v, int sl) {
    union { double d; int i[2]; } u, r;
    u.d = v;
    r.i[0] = __builtin_amdgcn_readlane(u.i[0], sl);
    r.i[1] = __builtin_amdgcn_readlane(u.i[1], sl);
    return r.d;
}

// ---------------------------------------------------------------------------
// One Gauss-Jordan step with compile-time K: template instantiation guarantees
// every row[] index is a constant -> array stays in VGPRs (no scratch).
// ---------------------------------------------------------------------------
template<int K>
__device__ __forceinline__ void gj_step(double (&row)[NA], bool& used,
                                        int& kown, int tid) {
    // --- pivot select: argmax |row[K]| over unused lanes, packed u32 ---
    // |x| as IEEE bits is monotonic for x>=0; low 6 bits carry the lane id.
    float mag = (float)fabs(row[K]);
    unsigned packed = (__float_as_uint(mag) & 0xFFFFFFC0u) | (unsigned)tid;
    if (used) packed = 0u;
    #pragma unroll
    for (int off = 32; off > 0; off >>= 1) {
        unsigned o = (unsigned)__shfl_xor((int)packed, off);
        packed = packed > o ? packed : o;
    }
    int prid = __builtin_amdgcn_readfirstlane((int)(packed & 63u));

    double pk  = bcast_lane(row[K], prid);
    double inv = 1.0 / pk;
    double f   = row[K];
    bool   isp = (tid == prid);
    if (isp) { used = true; kown = K; }

    // --- eliminate column K from every row (Gauss-Jordan). Skip c<=K:
    // those columns hold eliminated residuals that are never read again.
    #pragma unroll
    for (int c = K + 1; c < NA; ++c) {
        double pc = bcast_lane(row[c], prid) * inv;   // normalized pivot row
        row[c] = isp ? pc : row[c] - f * pc;
    }
}

template<int K>
__device__ __forceinline__ void gj_all(double (&row)[NA], bool& used,
                                       int& kown, int tid) {
    if constexpr (K < NP) {
        gj_step<K>(row, used, kown, tid);
        gj_all<K + 1>(row, used, kown, tid);
    }
}

// ---------------------------------------------------------------------------
// Stage 1: one wave per (batch,channel) system. Lane r owns row r of the
// 36x37 augmented matrix in fp64 VGPRs. Gauss-Jordan with partial pivoting;
// pivot row broadcast via v_readlane (no LDS round-trips, no barriers).
// The lane chosen at step k ends with x[k] in row[36].
// NOTE: every row[] access uses a compile-time index — a single runtime-
// indexed access (e.g. row[tid]) demotes the array to scratch (rule #20).
// ---------------------------------------------------------------------------
__global__ __launch_bounds__(64, 1) void tps_solve(const float* __restrict__ params,
                                                   float* __restrict__ Wout) {
    int sys = blockIdx.x;
    int b   = sys / 3;
    int ch  = sys % 3;
    const float* pp = params + (size_t)b * (6 * NK + 3);

    __shared__ float sxs[NK][3];
    int tid = threadIdx.x;
    for (int i = tid; i < NK * 3; i += 64) sxs[i / 3][i % 3] = pp[i];
    __syncthreads();

    float lam = pp[6 * NK + ch];

    // Build row `tid` in registers. Distances in fp32 (matches reference).
    double row[NA];
    #pragma unroll
    for (int c = 0; c < NA; ++c) row[c] = 0.0;

    if (tid < NK) {
        float x0 = sxs[tid][0], x1 = sxs[tid][1], x2 = sxs[tid][2];
        #pragma unroll
        for (int c = 0; c < NK; ++c) {
            float dx = x0 - sxs[c][0];
            float dy = x1 - sxs[c][1];
            float dz = x2 - sxs[c][2];
            float d  = hw_sqrtf(dx*dx + dy*dy + dz*dz);
            // diagonal: dist=0, K adds lambda*I -> select with CONSTANT index c
            row[c] = (c == tid) ? (double)lam : (double)d;
        }
        row[32]  = 1.0;
        row[33]  = (double)x0;
        row[34]  = (double)x1;
        row[35]  = (double)x2;
        row[36]  = (double)pp[3*NK + tid*3 + ch];   // rhs = ys[tid][ch]
    } else if (tid < NP) {
        // bottom rows: [1...1; xs^T] in cols 0..31, zeros elsewhere
        #pragma unroll
        for (int c = 0; c < NK; ++c)
            row[c] = (tid == 32) ? 1.0 : (double)sxs[c][tid - 33];
    }

    bool used = (tid >= NP);   // lanes 36..63 never pivot
    int  kown = -1;

    gj_all<0>(row, used, kown, tid);

    // lane chosen at step k holds x[k] = row[36]
    if (kown >= 0)
        Wout[((size_t)b * NP + kown) * 4 + ch] = (float)row[36];
}

// ---------------------------------------------------------------------------
// Stage 2: per-pixel spline evaluation, PX=8 pixels (24 floats = 6 float4)
// per thread. fimg = raw.reshape(B,HW,3) is a linear reinterpretation, and
// the output reshape is the identity on flat layout. (unchanged this round)
// ---------------------------------------------------------------------------
__global__ __launch_bounds__(256) void spline_apply(const float* __restrict__ raw,
                                                    const float* __restrict__ params,
                                                    const float4* __restrict__ Wk,
                                                    float* __restrict__ out,
                                                    int HW) {
    __shared__ float4 sX[NK];
    __shared__ float4 sW[NP];

    int b   = blockIdx.y;
    int tid = threadIdx.x;

    const float* pp = params + (size_t)b * (6 * NK + 3);
    if (tid < NK) sX[tid] = make_float4(pp[tid*3], pp[tid*3+1], pp[tid*3+2], 0.f);
    if (tid < NP) sW[tid] = Wk[(size_t)b * NP + tid];
    __syncthreads();

    int p8 = blockIdx.x * 256 + tid;          // 8-pixel group within batch
    if (p8 * PX >= HW) return;

    size_t off = (size_t)b * HW * 3 + (size_t)p8 * (PX * 3);
    const float4* src = (const float4*)(raw + off);
    float f[PX * 3];
    #pragma unroll
    for (int j = 0; j < PX * 3 / 4; ++j) {
        float4 v = src[j];
        f[j*4+0] = v.x; f[j*4+1] = v.y; f[j*4+2] = v.z; f[j*4+3] = v.w;
    }

    float4 wb  = sW[NK];                                    // bias row
    float4 w33 = sW[NK+1], w34 = sW[NK+2], w35 = sW[NK+3];  // linear rows
    float acc[PX * 3];
    #pragma unroll
    for (int p = 0; p < PX; ++p) {
        float c0 = f[p*3+0], c1 = f[p*3+1], c2 = f[p*3+2];
        acc[p*3+0] = wb.x + c0*w33.x + c1*w34.x + c2*w35.x;
        acc[p*3+1] = wb.y + c0*w33.y + c1*w34.y + c2*w35.y;
        acc[p*3+2] = wb.z + c0*w33.z + c1*w34.z + c2*w35.z;
    }

    #pragma unroll 4
    for (int k = 0; k < NK; ++k) {
        float4 x = sX[k];
        float4 w = sW[k];
        #pragma unroll
        for (int p = 0; p < PX; ++p) {
            float dx = f[p*3+0] - x.x;
            float dy = f[p*3+1] - x.y;
            float dz = f[p*3+2] - x.z;
            float d  = hw_sqrtf(dx*dx + dy*dy + dz*dz);
            acc[p*3+0] += d * w.x;
            acc[p*3+1] += d * w.y;
            acc[p*3+2] += d * w.z;
        }
    }

    float4* dst = (float4*)(out + off);
    #pragma unroll
    for (int j = 0; j < PX * 3 / 4; ++j)
        dst[j] = make_float4(acc[j*4+0], acc[j*4+1], acc[j*4+2], acc[j*4+3]);
}

extern "C" void kernel_launch(void* const* d_in, const int* in_sizes, int n_in,
                              void* d_out, int out_size, void* d_ws, size_t ws_size,
                              hipStream_t stream) {
    const float* raw    = (const float*)d_in[0];
    const float* params = (const float*)d_in[1];
    float* out = (float*)d_out;
    float* Wk  = (float*)d_ws;                 // [B][36][4] floats

    int B  = in_sizes[1] / (6 * NK + 3);
    int HW = in_sizes[0] / (B * 3);

    tps_solve<<<dim3(B * 3), dim3(64), 0, stream>>>(params, Wk);

    int groups = HW / PX;                      // HW = 200704, divisible by 8
    int bpb = (groups + 255) / 256;
    spline_apply<<<dim3(bpb, B), dim3(256), 0, stream>>>(
        raw, params, (const float4*)Wk, out, HW);
}

// Round 6
// 41.231 us; speedup vs baseline: 2.8774x; 1.1814x over previous
//
#include <hip/hip_runtime.h>
#include <math.h>

#define NK 32           // knots
#define NP 36           // NK + 4 (system size)
#define NA 37           // augmented columns (incl. rhs)
#define PX 8            // pixels per thread in apply

// hardware v_sqrt_f32 (~1 ulp) — __sqrtf collides with glibc math.h macros
__device__ __forceinline__ float hw_sqrtf(float x) {
    return __builtin_amdgcn_sqrtf(x);
}

// ---------------------------------------------------------------------------
// Full-wave (64-lane) max of an unsigned via DPP: row_shr 1/2/4/8 gives each
// row-of-16's inclusive max in lane 15 mod 16; row_bcast15 (rows 1,3) and
// row_bcast31 (rows 2,3) combine; lane 63 holds the wave max. All VALU —
// no LDS swizzle latency. Returns the wave-uniform max (SGPR via readlane).
// old=0 makes masked-out/invalid lanes contribute the identity for u32 max.
// ---------------------------------------------------------------------------
__device__ __forceinline__ unsigned wave_max64(unsigned x) {
    unsigned t;
    t = (unsigned)__builtin_amdgcn_update_dpp(0, (int)x, 0x111, 0xF, 0xF, true); x = x > t ? x : t; // row_shr:1
    t = (unsigned)__builtin_amdgcn_update_dpp(0, (int)x, 0x112, 0xF, 0xF, true); x = x > t ? x : t; // row_shr:2
    t = (unsigned)__builtin_amdgcn_update_dpp(0, (int)x, 0x114, 0xF, 0xF, true); x = x > t ? x : t; // row_shr:4
    t = (unsigned)__builtin_amdgcn_update_dpp(0, (int)x, 0x118, 0xF, 0xF, true); x = x > t ? x : t; // row_shr:8
    t = (unsigned)__builtin_amdgcn_update_dpp(0, (int)x, 0x142, 0xA, 0xF, true); x = x > t ? x : t; // row_bcast:15
    t = (unsigned)__builtin_amdgcn_update_dpp(0, (int)x, 0x143, 0xC, 0xF, true); x = x > t ? x : t; // row_bcast:31
    return (unsigned)__builtin_amdgcn_readlane((int)x, 63);
}

// broadcast float from lane sl (wave-uniform) — pure bit ops, no union/alloca
__device__ __forceinline__ float bcastf(float v, int sl) {
    return __int_as_float(__builtin_amdgcn_readlane(__float_as_int(v), sl));
}

// ---------------------------------------------------------------------------
// Stage 1: one wave per (batch,channel) system. Lane r owns row r of the
// 36x37 augmented matrix in fp32 VGPRs. Flat straight-line Gauss-Jordan with
// partial pivoting (36 macro-expanded steps): no recursion, no references,
// every row[] index is a literal -> SROA must keep the array in registers.
// The lane chosen at step K ends with x[K] in row[36].
// ---------------------------------------------------------------------------
__global__ __launch_bounds__(64, 1) void tps_solve(const float* __restrict__ params,
                                                   float* __restrict__ Wout) {
    int sys = blockIdx.x;
    int b   = sys / 3;
    int ch  = sys % 3;
    const float* pp = params + (size_t)b * (6 * NK + 3);

    __shared__ float sxs[NK][3];
    int tid = threadIdx.x;
    for (int i = tid; i < NK * 3; i += 64) sxs[i / 3][i % 3] = pp[i];
    __syncthreads();

    float lam = pp[6 * NK + ch];

    float row[NA];
    #pragma unroll
    for (int c = 0; c < NA; ++c) row[c] = 0.0f;

    if (tid < NK) {
        float x0 = sxs[tid][0], x1 = sxs[tid][1], x2 = sxs[tid][2];
        #pragma unroll
        for (int c = 0; c < NK; ++c) {
            float dx = x0 - sxs[c][0];
            float dy = x1 - sxs[c][1];
            float dz = x2 - sxs[c][2];
            float d  = hw_sqrtf(dx*dx + dy*dy + dz*dz);
            row[c] = (c == tid) ? lam : d;   // diag: dist=0, +lambda*I
        }
        row[32] = 1.0f;
        row[33] = x0;
        row[34] = x1;
        row[35] = x2;
        row[36] = pp[3*NK + tid*3 + ch];     // rhs = ys[tid][ch]
    } else if (tid < NP) {
        #pragma unroll
        for (int c = 0; c < NK; ++c)
            row[c] = (tid == 32) ? 1.0f : sxs[c][tid - 33];   // [1...1; xs^T]
    }

    unsigned used = (tid >= NP) ? 1u : 0u;   // lanes 36..63 never pivot
    int kown = -1;

// One Gauss-Jordan step; K is a literal. Pivot = argmax |row[K]| over unused
// lanes, packed (magnitude-bits & ~63)|lane (monotonic for |x|>=0). Any
// nonzero pivot is algebraically valid. Columns <= K are dead residuals.
#define GJ_STEP(K) do {                                                           \
    unsigned pk_ = (__float_as_uint(fabsf(row[(K)])) & 0xFFFFFFC0u) | (unsigned)tid; \
    pk_ = used ? 0u : pk_;                                                        \
    int prid = (int)(wave_max64(pk_) & 63u);                                      \
    float pv  = bcastf(row[(K)], prid);                                           \
    float inv = 1.0f / pv;                                                        \
    float f   = row[(K)];                                                         \
    bool  isp = (tid == prid);                                                    \
    if (isp) { used = 1u; kown = (K); }                                           \
    _Pragma("unroll")                                                             \
    for (int c = (K) + 1; c < NA; ++c) {                                          \
        float pc = bcastf(row[c], prid) * inv;                                    \
        row[c] = isp ? pc : row[c] - f * pc;                                      \
    }                                                                             \
} while (0)

    GJ_STEP(0);  GJ_STEP(1);  GJ_STEP(2);  GJ_STEP(3);  GJ_STEP(4);  GJ_STEP(5);
    GJ_STEP(6);  GJ_STEP(7);  GJ_STEP(8);  GJ_STEP(9);  GJ_STEP(10); GJ_STEP(11);
    GJ_STEP(12); GJ_STEP(13); GJ_STEP(14); GJ_STEP(15); GJ_STEP(16); GJ_STEP(17);
    GJ_STEP(18); GJ_STEP(19); GJ_STEP(20); GJ_STEP(21); GJ_STEP(22); GJ_STEP(23);
    GJ_STEP(24); GJ_STEP(25); GJ_STEP(26); GJ_STEP(27); GJ_STEP(28); GJ_STEP(29);
    GJ_STEP(30); GJ_STEP(31); GJ_STEP(32); GJ_STEP(33); GJ_STEP(34); GJ_STEP(35);
#undef GJ_STEP

    // lane chosen at step k holds x[k] = row[36]
    if (kown >= 0)
        Wout[((size_t)b * NP + kown) * 4 + ch] = row[36];
}

// ---------------------------------------------------------------------------
// Stage 2: per-pixel spline evaluation, PX=8 pixels (24 floats = 6 float4)
// per thread. fimg = raw.reshape(B,HW,3) is a linear reinterpretation, and
// the output reshape is the identity on flat layout. (unchanged — ~87% of
// achievable HBM BW already)
// ---------------------------------------------------------------------------
__global__ __launch_bounds__(256) void spline_apply(const float* __restrict__ raw,
                                                    const float* __restrict__ params,
                                                    const float4* __restrict__ Wk,
                                                    float* __restrict__ out,
                                                    int HW) {
    __shared__ float4 sX[NK];
    __shared__ float4 sW[NP];

    int b   = blockIdx.y;
    int tid = threadIdx.x;

    const float* pp = params + (size_t)b * (6 * NK + 3);
    if (tid < NK) sX[tid] = make_float4(pp[tid*3], pp[tid*3+1], pp[tid*3+2], 0.f);
    if (tid < NP) sW[tid] = Wk[(size_t)b * NP + tid];
    __syncthreads();

    int p8 = blockIdx.x * 256 + tid;          // 8-pixel group within batch
    if (p8 * PX >= HW) return;

    size_t off = (size_t)b * HW * 3 + (size_t)p8 * (PX * 3);
    const float4* src = (const float4*)(raw + off);
    float f[PX * 3];
    #pragma unroll
    for (int j = 0; j < PX * 3 / 4; ++j) {
        float4 v = src[j];
        f[j*4+0] = v.x; f[j*4+1] = v.y; f[j*4+2] = v.z; f[j*4+3] = v.w;
    }

    float4 wb  = sW[NK];                                    // bias row
    float4 w33 = sW[NK+1], w34 = sW[NK+2], w35 = sW[NK+3];  // linear rows
    float acc[PX * 3];
    #pragma unroll
    for (int p = 0; p < PX; ++p) {
        float c0 = f[p*3+0], c1 = f[p*3+1], c2 = f[p*3+2];
        acc[p*3+0] = wb.x + c0*w33.x + c1*w34.x + c2*w35.x;
        acc[p*3+1] = wb.y + c0*w33.y + c1*w34.y + c2*w35.y;
        acc[p*3+2] = wb.z + c0*w33.z + c1*w34.z + c2*w35.z;
    }

    #pragma unroll 4
    for (int k = 0; k < NK; ++k) {
        float4 x = sX[k];
        float4 w = sW[k];
        #pragma unroll
        for (int p = 0; p < PX; ++p) {
            float dx = f[p*3+0] - x.x;
            float dy = f[p*3+1] - x.y;
            float dz = f[p*3+2] - x.z;
            float d  = hw_sqrtf(dx*dx + dy*dy + dz*dz);
            acc[p*3+0] += d * w.x;
            acc[p*3+1] += d * w.y;
            acc[p*3+2] += d * w.z;
        }
    }

    float4* dst = (float4*)(out + off);
    #pragma unroll
    for (int j = 0; j < PX * 3 / 4; ++j)
        dst[j] = make_float4(acc[j*4+0], acc[j*4+1], acc[j*4+2], acc[j*4+3]);
}

extern "C" void kernel_launch(void* const* d_in, const int* in_sizes, int n_in,
                              void* d_out, int out_size, void* d_ws, size_t ws_size,
                              hipStream_t stream) {
    const float* raw    = (const float*)d_in[0];
    const float* params = (const float*)d_in[1];
    float* out = (float*)d_out;
    float* Wk  = (float*)d_ws;                 // [B][36][4] floats

    int B  = in_sizes[1] / (6 * NK + 3);
    int HW = in_sizes[0] / (B * 3);

    tps_solve<<<dim3(B * 3), dim3(64), 0, stream>>>(params, Wk);

    int groups = HW / PX;                      // HW = 200704, divisible by 8
    int bpb = (groups + 255) / 256;
    spline_apply<<<dim3(bpb, B), dim3(256), 0, stream>>>(
        raw, params, (const float4*)Wk, out, HW);
}